// Round 6
// baseline (138.372 us; speedup 1.0000x reference)
//
#include <hip/hip_runtime.h>
#include <hip/hip_bf16.h>

// Linear layer: out[M,N] = x[M,K] @ W[N,K]^T + b[N], fp32 in/out.
// M=32768, N=512, K=512. bf16 MFMA, fp32 accumulate.
// R5-R9 history: 2-phase 128x128 dbuf structure plateaus at 53-56 us
//   (312 TF == m102's measured m97-structure value at this FLOP size).
//   R9 falsified the vmcnt-drain theory (lgkm-only barrier: no change).
// R10 (this): deep-ILP regime (T2+T3+T5 class). BM=128, BN=256 (full N
//   inside one block -> A reuse intra-block), BK=64, 512 thr / 8 waves
//   (2Mx4N, 64x64/wave -> acc 64 VGPR). grid=256 = 1 block/CU, no tail.
//   LDS 96 KB: dbuf bf16 tiles, XOR swizzle byte^=(row&7)<<4 (frag reads
//   2-way = free). Per K-tile: issue 12 f32 loads for tile k+1 (lead-1,
//   48 VGPR in flight), 2 phases x 16 MFMA with setprio, cvt+ds_write,
//   lgkm-only barrier (R9-verified idiom). Two n-passes reuse hot A.
//   VGPR budget ~185 (no min-waves bound -> no R6/R8 spill trap).

#define M_DIM 32768
#define N_DIM 512
#define K_DIM 512
#define BM 128
#define BN 256
#define BK 64          // k-tile width (f32 words); 8 tiles per pass
#define KT (K_DIM / BK)

typedef __bf16 bf16x8 __attribute__((ext_vector_type(8)));
typedef __bf16 bf16x4 __attribute__((ext_vector_type(4)));
typedef float floatx4 __attribute__((ext_vector_type(4)));

__global__ __launch_bounds__(512, 1) void linear_8p(
    const float* __restrict__ A,    // [M, K]
    const float* __restrict__ W,    // [N, K]
    const float* __restrict__ bias, // [N]
    float* __restrict__ C)          // [M, N]
{
    // LDS rows = 64 bf16 = 128 B. Swizzle: 16B-chunk c' = c ^ (row&7).
    __shared__ __bf16 sA[2][BM * BK];   // 2 x 16 KB
    __shared__ __bf16 sW[2][BN * BK];   // 2 x 32 KB   (total 96 KB)

    const int t = threadIdx.x;
    const int mBase = blockIdx.x * BM;  // 256 blocks = 1 per CU

    const int wid = t >> 6;
    const int lane = t & 63;
    const int mW = (wid >> 2) * 64;     // 2 wave-rows
    const int nW = (wid & 3) * 64;      // 4 wave-cols
    const int kh = lane >> 4;
    const int l16 = lane & 15;
    const int sxz = (l16 & 7) << 3;     // frag-read swizzle term (elems)

    // Staging map: thread covers 16B column c16 of row-groups rg+32p.
    const int c16 = t & 15;
    const int rg = t >> 4;              // 0..31
    const float* aCol = A + (size_t)mBase * K_DIM + c16 * 4;
    const float* wCol = W + c16 * 4;

    // LDS write offsets (elems): r*64 + ((c16*4) ^ ((r&7)<<3))
    int aWofs[4], wWofs[8];
#pragma unroll
    for (int p = 0; p < 4; ++p) {
        const int r = rg + 32 * p;
        aWofs[p] = r * BK + ((c16 * 4) ^ ((r & 7) << 3));
    }
#pragma unroll
    for (int p = 0; p < 8; ++p) {
        const int r = rg + 32 * p;
        wWofs[p] = r * BK + ((c16 * 4) ^ ((r & 7) << 3));
    }

#define STAGE_LOAD(nB, kt)                                                    \
    {                                                                         \
        const float* ap = aCol + (size_t)(kt) * BK;                           \
        const float* wp = wCol + (size_t)(nB) * K_DIM + (size_t)(kt) * BK;    \
        _Pragma("unroll") for (int p = 0; p < 4; ++p)                         \
            ld[p] = *(const floatx4*)(ap + (size_t)(rg + 32 * p) * K_DIM);    \
        _Pragma("unroll") for (int p = 0; p < 8; ++p)                         \
            ld[4 + p] = *(const floatx4*)(wp + (size_t)(rg + 32 * p) *        \
                                          K_DIM);                             \
    }

#define STAGE_WRITE(bufi)                                                     \
    {                                                                         \
        _Pragma("unroll") for (int p = 0; p < 4; ++p) {                       \
            bf16x4 v;                                                         \
            _Pragma("unroll") for (int j = 0; j < 4; ++j)                     \
                v[j] = (__bf16)ld[p][j];                                      \
            *(bf16x4*)&sA[(bufi)][aWofs[p]] = v;                              \
        }                                                                     \
        _Pragma("unroll") for (int p = 0; p < 8; ++p) {                       \
            bf16x4 v;                                                         \
            _Pragma("unroll") for (int j = 0; j < 4; ++j)                     \
                v[j] = (__bf16)ld[4 + p][j];                                  \
            *(bf16x4*)&sW[(bufi)][wWofs[p]] = v;                              \
        }                                                                     \
    }

    // One 16-MFMA phase: ks selects the 32-wide K half of the tile.
    // Frag elem addr: row*64 + ((ks*32 + kh*8) ^ sxz); row&7 == l16&7.
#define PHASE(curp, ksp)                                                      \
    {                                                                         \
        bf16x8 aF[4], wF[4];                                                  \
        _Pragma("unroll") for (int i = 0; i < 4; ++i) {                       \
            aF[i] = *(const bf16x8*)&sA[(curp)][(mW + i * 16 + l16) * BK +    \
                                               (((ksp)*32 + kh * 8) ^ sxz)];  \
            wF[i] = *(const bf16x8*)&sW[(curp)][(nW + i * 16 + l16) * BK +    \
                                               (((ksp)*32 + kh * 8) ^ sxz)];  \
        }                                                                     \
        __builtin_amdgcn_s_setprio(1);                                        \
        _Pragma("unroll") for (int mi = 0; mi < 4; ++mi)                      \
            _Pragma("unroll") for (int ni = 0; ni < 4; ++ni)                  \
                acc[mi][ni] = __builtin_amdgcn_mfma_f32_16x16x32_bf16(        \
                    aF[mi], wF[ni], acc[mi][ni], 0, 0, 0);                    \
        __builtin_amdgcn_s_setprio(0);                                        \
    }

    for (int np = 0; np < 2; ++np) {
        const int nB = np * BN;

        floatx4 acc[4][4];
#pragma unroll
        for (int i = 0; i < 4; ++i)
#pragma unroll
            for (int j = 0; j < 4; ++j)
                acc[i][j] = (floatx4)0.f;

        floatx4 ld[12];
        // prologue: stage tile 0 into buf 0
        STAGE_LOAD(nB, 0);
        STAGE_WRITE(0);
        asm volatile("s_waitcnt lgkmcnt(0)" ::: "memory");
        __builtin_amdgcn_s_barrier();

        int cur = 0;
        for (int kt = 0; kt < KT; ++kt) {
            if (kt + 1 < KT)
                STAGE_LOAD(nB, kt + 1);       // lead-1 issue (48 VGPR)
            __builtin_amdgcn_sched_barrier(0); // pin issue before compute
            PHASE(cur, 0);
            PHASE(cur, 1);
            if (kt + 1 < KT)
                STAGE_WRITE(cur ^ 1);          // cvt + ds_write (vmcnt here)
            asm volatile("s_waitcnt lgkmcnt(0)" ::: "memory");
            __builtin_amdgcn_s_barrier();      // lgkm-only (R9-verified)
            cur ^= 1;
        }

        // Epilogue: D mapping col = lane&15, row = (lane>>4)*4 + reg
        // (verified in R5-R9).
#pragma unroll
        for (int ni = 0; ni < 4; ++ni) {
            const int gcol = nB + nW + ni * 16 + l16;
            const float bv = bias[gcol];
#pragma unroll
            for (int mi = 0; mi < 4; ++mi) {
                const int rowB = mBase + mW + mi * 16 + kh * 4;
#pragma unroll
                for (int r = 0; r < 4; ++r)
                    C[(size_t)(rowB + r) * N_DIM + gcol] = acc[mi][ni][r] + bv;
            }
        }
        // np=1 prologue writes buf0 (last read at kt=6, drained) — no race.
    }

#undef STAGE_LOAD
#undef STAGE_WRITE
#undef PHASE
}

extern "C" void kernel_launch(void* const* d_in, const int* in_sizes, int n_in,
                              void* d_out, int out_size, void* d_ws, size_t ws_size,
                              hipStream_t stream) {
    const float* x = (const float*)d_in[0];
    const float* w = (const float*)d_in[1];
    const float* b = (const float*)d_in[2];
    float* out = (float*)d_out;

    dim3 grid(M_DIM / BM);   // 256 blocks = 1 per CU, zero tail
    dim3 block(512);
    linear_8p<<<grid, block, 0, stream>>>(x, w, b, out);
}